// Round 5
// baseline (31.270 us; speedup 1.0000x reference)
//
#include <hip/hip_runtime.h>
#include <math.h>

constexpr int BB   = 2;
constexpr int NN   = 512;
constexpr int FIN  = 256;
constexpr int FOUT = 128;

// ---------------------------------------------------------------------------
// Kernel A: Wh = x@W and u_i = sum_o a_o*Wh[i,o]
// 256 blocks x 512 thr, 4 rows/block.
// Lane layout: rl = t&3 (row), og = (t>>2)&31 (o-quad), fs = t>>7 (f-slice).
// The 4 rl-duplicates of each W float4 are ADJACENT LANES -> wave coalescer
// dedups to one 256B request -> W traffic 128KB/block (was ~512KB).
// ---------------------------------------------------------------------------
__global__ __launch_bounds__(512) void wh_u_kernel(const float* __restrict__ x,
                                                   const float* __restrict__ W,
                                                   const float* __restrict__ a_fc,
                                                   float* __restrict__ Wh,
                                                   float* __restrict__ u) {
    __shared__ float xs[4][260];    // pad 260: rl-broadcast reads conflict-free
    __shared__ float upart[8][4];

    const int t  = threadIdx.x;
    const int g0 = blockIdx.x * 4;

    if (t < 256) {
        const int row = t >> 6, c4 = t & 63;
        *(float4*)&xs[row][c4 * 4] =
            ((const float4*)(x + (size_t)g0 * FIN))[t];
    }
    __syncthreads();

    const int rl = t & 3;
    const int og = (t >> 2) & 31;
    const int fs = t >> 7;
    const float* xr = &xs[rl][fs * 64];
    const float4* W4 = (const float4*)W;

    float4 acc = {0.f, 0.f, 0.f, 0.f};
#pragma unroll 8
    for (int f = 0; f < 64; ++f) {
        const float  xv = xr[f];
        const float4 wv = W4[(size_t)(fs * 64 + f) * 32 + og];
        acc.x = fmaf(xv, wv.x, acc.x);
        acc.y = fmaf(xv, wv.y, acc.y);
        acc.z = fmaf(xv, wv.z, acc.z);
        acc.w = fmaf(xv, wv.w, acc.w);
    }
    // Wh is summed over fs across waves? No: each (rl,og) appears once per fs;
    // need cross-fs sum. Do it through LDS like R4 but with the new layout.
    __shared__ float4 part[4][4][32];
    part[rl][fs][og] = acc;
    __syncthreads();

    float4 w4 = {0.f, 0.f, 0.f, 0.f};
    if (t < 128) {   // t = rl + og*4 layout for the combine: reuse rl/og decode
        const int crl = t & 3;
        const int cog = t >> 2;
        const float4 s0 = part[crl][0][cog];
        const float4 s1 = part[crl][1][cog];
        const float4 s2 = part[crl][2][cog];
        const float4 s3 = part[crl][3][cog];
        w4.x = (s0.x + s1.x) + (s2.x + s3.x);
        w4.y = (s0.y + s1.y) + (s2.y + s3.y);
        w4.z = (s0.z + s1.z) + (s2.z + s3.z);
        w4.w = (s0.w + s1.w) + (s2.w + s3.w);
        ((float4*)(Wh + (size_t)(g0 + crl) * FOUT))[cog] = w4;

        const float4 a4 = ((const float4*)a_fc)[cog];
        float pa = w4.x * a4.x + w4.y * a4.y + w4.z * a4.z + w4.w * a4.w;
        // sum over og (stride-4 lanes share rl)
#pragma unroll
        for (int off = 32; off >= 4; off >>= 1) pa += __shfl_down(pa, off);
        if ((t & 63) < 4) upart[t >> 6][t & 3] = pa;
    }
    __syncthreads();
    if (t < 4) {
        float s = 0.f;
#pragma unroll
        for (int w = 0; w < 2; ++w) s += upart[w][t];
        u[g0 + t] = s;
    }
}

// ---------------------------------------------------------------------------
// Kernel B: e[i,j] = 0.6(u_i+u_j) + S_ij,  S_ij = sum_o (0.4 a_o)|Wh_io+Wh_jo|
// SYMMETRY: S_ij = S_ji. Straight set = {(i,j): j >= 64*floor(i/64)} (tiles
// 64i x 8j, J in [8I..63]); cells with I < J>>3 are mirrored to (j,i).
// Proven: straight-set U mirrors = full matrix, intersection empty.
// 576 blocks x 256 thr. j-panel read via wave-uniform global loads (L1),
// i-panel staged in LDS (coalesced) then register-preloaded.
// sumsq weight: 2 if tile mirrors, else 1.
// ---------------------------------------------------------------------------
__global__ __launch_bounds__(256) void e_sym_kernel(const float* __restrict__ Wh,
                                                    const float* __restrict__ u_g,
                                                    const float* __restrict__ a_fc,
                                                    float* __restrict__ e_buf,
                                                    float* __restrict__ partials) {
    __shared__ float whi[64][132];
    __shared__ float usi_l[64];
    __shared__ float usj_l[8];
    __shared__ float parts[8][4][66];
    __shared__ float red[4];

    // decode (b, I, J): per-batch tile count 288, C(I) = 4I(17-I)
    int bx = blockIdx.x;
    int b = 0;
    if (bx >= 288) { b = 1; bx -= 288; }
    int I = 0;
#pragma unroll
    for (int k = 7; k >= 1; --k) {
        if (bx >= 4 * k * (17 - k)) { I = k; break; }
    }
    const int J  = 8 * I + (bx - 4 * I * (17 - I));
    const int i0 = I * 64, j0 = J * 8;
    const bool mir = (I < (J >> 3));

    const int t = threadIdx.x;
    const float* whb  = Wh + (size_t)(b * NN) * FOUT;
    const float4* whb4 = (const float4*)whb;

    // stage i-panel (64 rows x 128) coalesced; u slices
#pragma unroll
    for (int it = 0; it < 8; ++it) {
        const int idx = it * 256 + t;
        const int row = idx >> 5, c4 = idx & 31;
        *(float4*)&whi[row][c4 * 4] = whb4[(size_t)(i0 + row) * 32 + c4];
    }
    if (t < 64)            usi_l[t]      = u_g[b * NN + i0 + t];
    else if (t < 72)       usj_l[t - 64] = u_g[b * NN + j0 + (t - 64)];
    __syncthreads();

    const int w    = t >> 6;
    const int lane = t & 63;
    const int ob   = (w & 3) * 32;

    float4 iv[8], av[8];
#pragma unroll
    for (int k = 0; k < 8; ++k) {
        iv[k] = *(const float4*)&whi[lane][ob + 4 * k];
        av[k] = ((const float4*)a_fc)[(ob >> 2) + k];
        av[k].x *= 0.4f; av[k].y *= 0.4f; av[k].z *= 0.4f; av[k].w *= 0.4f;
    }

#pragma unroll
    for (int j = 0; j < 8; ++j) {
        float4 acc = {0.f, 0.f, 0.f, 0.f};
#pragma unroll
        for (int k = 0; k < 8; ++k) {
            const float4 jv = whb4[(size_t)(j0 + j) * 32 + (ob >> 2) + k];
            float s;
            s = iv[k].x + jv.x; acc.x = fmaf(av[k].x, fabsf(s), acc.x);
            s = iv[k].y + jv.y; acc.y = fmaf(av[k].y, fabsf(s), acc.y);
            s = iv[k].z + jv.z; acc.z = fmaf(av[k].z, fabsf(s), acc.z);
            s = iv[k].w + jv.w; acc.w = fmaf(av[k].w, fabsf(s), acc.w);
        }
        parts[j][w][lane] = (acc.x + acc.y) + (acc.z + acc.w);
    }
    __syncthreads();

    // combine: t<128 straight (i = t>>1, 4 j's); t>=128 mirror writes
    float ss = 0.f;
    if (t < 128) {
        const int i  = t >> 1;
        const int jq = (t & 1) * 4;
        const float ui = usi_l[i];
        float4 e4;
        float ev[4];
#pragma unroll
        for (int jj = 0; jj < 4; ++jj) {
            const int j = jq + jj;
            const float S = (parts[j][0][i] + parts[j][1][i]) +
                            (parts[j][2][i] + parts[j][3][i]);
            ev[jj] = fmaf(0.6f, ui + usj_l[j], S);
            ss = fmaf(ev[jj], ev[jj], ss);
        }
        ss *= (mir ? 2.0f : 1.0f);
        e4.x = ev[0]; e4.y = ev[1]; e4.z = ev[2]; e4.w = ev[3];
        *(float4*)&e_buf[(size_t)(b * NN + i0 + i) * NN + j0 + jq] = e4;
    } else if (mir) {
        const int m  = t - 128;
        const int j  = m >> 4;
        const int iq = m & 15;
        const float uj = usj_l[j];
        float4 e4;
        float ev[4];
#pragma unroll
        for (int ii = 0; ii < 4; ++ii) {
            const int i = 4 * iq + ii;
            const float S = (parts[j][0][i] + parts[j][1][i]) +
                            (parts[j][2][i] + parts[j][3][i]);
            ev[ii] = fmaf(0.6f, usi_l[i] + uj, S);
        }
        e4.x = ev[0]; e4.y = ev[1]; e4.z = ev[2]; e4.w = ev[3];
        *(float4*)&e_buf[(size_t)(b * NN + j0 + j) * NN + i0 + 4 * iq] = e4;
    }

#pragma unroll
    for (int off = 32; off; off >>= 1) ss += __shfl_down(ss, off);
    if ((t & 63) == 0) red[t >> 6] = ss;
    __syncthreads();
    if (t == 0)
        partials[blockIdx.x] = (red[0] + red[1]) + (red[2] + red[3]);
}

// ---------------------------------------------------------------------------
// Kernel C: norm -> mask -> softmax -> att@Wh -> elu  (as R4; 576 partials)
// 512 blocks x 256 thr: (4 rows) x (64-o half). Wave w owns row w.
// ---------------------------------------------------------------------------
__global__ __launch_bounds__(256) void softmax_pv_kernel(
        const float* __restrict__ e_buf, const int* __restrict__ adj,
        const float* __restrict__ Wh, const float* __restrict__ partials,
        float* __restrict__ out) {
    __shared__ float p[4][NN];
    __shared__ float hb[3][4][64];
    __shared__ float red[4];
    __shared__ float rsv[4];

    const int t    = threadIdx.x;
    const int w    = t >> 6;
    const int lane = t & 63;

    float v = partials[t] + partials[t + 256];
    if (t < 64) v += partials[t + 512];
#pragma unroll
    for (int off = 32; off; off >>= 1) v += __shfl_down(v, off);
    if (lane == 0) red[w] = v;
    __syncthreads();
    const float inv_norm = 1.0f / sqrtf((red[0] + red[1]) + (red[2] + red[3]));

    const int g0  = (blockIdx.x & 255) * 4;
    const int row = g0 + w;

    const float4* er4 = (const float4*)(e_buf + (size_t)row * NN);
    const int4*   ad4 = (const int4*)(adj + (size_t)row * NN);
    const float4 ea = er4[lane],     eb = er4[lane + 64];
    const int4   aa = ad4[lane],     ab = ad4[lane + 64];

    float va[8];
    va[0] = aa.x ? ea.x * inv_norm : -INFINITY;
    va[1] = aa.y ? ea.y * inv_norm : -INFINITY;
    va[2] = aa.z ? ea.z * inv_norm : -INFINITY;
    va[3] = aa.w ? ea.w * inv_norm : -INFINITY;
    va[4] = ab.x ? eb.x * inv_norm : -INFINITY;
    va[5] = ab.y ? eb.y * inv_norm : -INFINITY;
    va[6] = ab.z ? eb.z * inv_norm : -INFINITY;
    va[7] = ab.w ? eb.w * inv_norm : -INFINITY;

    float mx = va[0];
#pragma unroll
    for (int c = 1; c < 8; ++c) mx = fmaxf(mx, va[c]);
#pragma unroll
    for (int off = 32; off; off >>= 1) mx = fmaxf(mx, __shfl_xor(mx, off));

    float pv[8], sum = 0.f;
#pragma unroll
    for (int c = 0; c < 8; ++c) { pv[c] = expf(va[c] - mx); sum += pv[c]; }
    float4 pa = {pv[0], pv[1], pv[2], pv[3]};
    float4 pb = {pv[4], pv[5], pv[6], pv[7]};
    ((float4*)&p[w][0])[lane]      = pa;
    ((float4*)&p[w][0])[lane + 64] = pb;

#pragma unroll
    for (int off = 32; off; off >>= 1) sum += __shfl_xor(sum, off);
    if (lane == 0) rsv[w] = 1.0f / sum;
    __syncthreads();

    const int oo = lane;
    const int o  = (blockIdx.x >> 8) * 64 + oo;
    const int b  = g0 >> 9;
    const float* whb = Wh + (size_t)(b * NN) * FOUT;
    const int j0 = w * 128;

    float acc[4] = {0.f, 0.f, 0.f, 0.f};
    for (int j = j0; j < j0 + 128; j += 4) {
        const float4 p0 = *(const float4*)&p[0][j];
        const float4 p1 = *(const float4*)&p[1][j];
        const float4 p2 = *(const float4*)&p[2][j];
        const float4 p3 = *(const float4*)&p[3][j];
        const float q0[4] = {p0.x, p0.y, p0.z, p0.w};
        const float q1[4] = {p1.x, p1.y, p1.z, p1.w};
        const float q2[4] = {p2.x, p2.y, p2.z, p2.w};
        const float q3[4] = {p3.x, p3.y, p3.z, p3.w};
#pragma unroll
        for (int q = 0; q < 4; ++q) {
            const float wv = whb[(size_t)(j + q) * FOUT + o];
            acc[0] = fmaf(q0[q], wv, acc[0]);
            acc[1] = fmaf(q1[q], wv, acc[1]);
            acc[2] = fmaf(q2[q], wv, acc[2]);
            acc[3] = fmaf(q3[q], wv, acc[3]);
        }
    }

    if (w) {
        hb[w - 1][0][oo] = acc[0];
        hb[w - 1][1][oo] = acc[1];
        hb[w - 1][2][oo] = acc[2];
        hb[w - 1][3][oo] = acc[3];
    }
    __syncthreads();
    if (w == 0) {
#pragma unroll
        for (int r = 0; r < 4; ++r) {
            const float hv = (acc[r] + hb[0][r][oo] + hb[1][r][oo] + hb[2][r][oo]) * rsv[r];
            out[(size_t)(g0 + r) * FOUT + o] = (hv > 0.f) ? hv : expm1f(hv);
        }
    }
}

// ---------------------------------------------------------------------------
extern "C" void kernel_launch(void* const* d_in, const int* in_sizes, int n_in,
                              void* d_out, int out_size, void* d_ws, size_t ws_size,
                              hipStream_t stream) {
    const float* x    = (const float*)d_in[0];
    const int*   adj  = (const int*)d_in[1];
    const float* W    = (const float*)d_in[2];
    const float* a_fc = (const float*)d_in[3];
    float* out = (float*)d_out;

    float* ws       = (float*)d_ws;
    float* Wh       = ws;                        // 131072 floats
    float* u        = ws + 131072;               // 1024
    float* partials = ws + 131072 + 1024;        // 1024 (576 used)
    float* e_buf    = ws + 131072 + 2048;        // 524288

    wh_u_kernel<<<dim3(BB * NN / 4), dim3(512), 0, stream>>>(x, W, a_fc, Wh, u);
    e_sym_kernel<<<dim3(576), dim3(256), 0, stream>>>(Wh, u, a_fc, e_buf, partials);
    softmax_pv_kernel<<<dim3(512), dim3(256), 0, stream>>>(e_buf, adj, Wh, partials, out);
}